// Round 3
// baseline (402.285 us; speedup 1.0000x reference)
//
#include <hip/hip_runtime.h>

// SpatialAttention fp32: B=128, C=3, H=W=256, 8x8 patches, FEAT=192, ENC=16.
// R3: 8 lanes per patch (sub = tid&7 owns features 24*sub..24*sub+23).
//  - 131072 patches * 8 = 1M threads = 16384 waves (vs 2048 in R2: occupancy
//    was 22% -> latency-bound at 162 us).
//  - acc[16] reduced across the 8-lane group via shfl_xor(1,2,4).
//  - decoder outputs o[24] kept in registers: no pass-2 recompute.
//  - softmax needs no max-subtraction: out = relu(...) in [0,~12].

constexpr int NPATCH = 128 * 32 * 32;
constexpr float L2E = 1.4426950408889634f;

__global__ __launch_bounds__(256, 4) void spatial_attn(
    const float* __restrict__ x,      // [128][3][256][256]
    const float* __restrict__ Wenc,   // [16][192]
    const float* __restrict__ benc,   // [16]
    const float* __restrict__ Wdec,   // [192][16]
    const float* __restrict__ bdec,   // [192]
    float* __restrict__ y)            // [128][3][256][256]
{
  const int tid = threadIdx.x;
  const int sub = tid & 7;                       // which 24-feature chunk
  const int p   = blockIdx.x * 32 + (tid >> 3);  // 32 patches per block
  const int b   = p >> 10;
  const int ii  = (p >> 5) & 31;
  const int jj  = p & 31;
  // element offset of (c,r) row-slice: base + c*65536 + r*256
  const size_t base = (size_t)b * 196608 + (size_t)ii * 2048 + (size_t)jj * 8;

  // ---- Load this lane's 24 x values (3 slices of 8, coalesced float4) ----
  float xv[24];
  #pragma unroll
  for (int t = 0; t < 3; ++t) {
    const int cr = 3 * sub + t;
    const float* src = x + base + (cr >> 3) * 65536 + (cr & 7) * 256;
    const float4 v0 = *(const float4*)(src);
    const float4 v1 = *(const float4*)(src + 4);
    xv[t*8+0]=v0.x; xv[t*8+1]=v0.y; xv[t*8+2]=v0.z; xv[t*8+3]=v0.w;
    xv[t*8+4]=v1.x; xv[t*8+5]=v1.y; xv[t*8+6]=v1.z; xv[t*8+7]=v1.w;
  }

  // ---- Encoder partial: acc[e] = sum over this lane's 24 features ----
  float acc[16];
  #pragma unroll
  for (int e = 0; e < 16; ++e) {
    const float* w = Wenc + e * 192 + sub * 24;
    float a = 0.0f;
    #pragma unroll
    for (int q = 0; q < 6; ++q) {
      const float4 wv = *(const float4*)(w + 4 * q);
      a = fmaf(wv.x, xv[4*q+0], a);
      a = fmaf(wv.y, xv[4*q+1], a);
      a = fmaf(wv.z, xv[4*q+2], a);
      a = fmaf(wv.w, xv[4*q+3], a);
    }
    acc[e] = a;
  }
  // ---- Reduce across the 8-lane patch group, add bias, relu ----
  #pragma unroll
  for (int e = 0; e < 16; ++e) {
    float a = acc[e];
    a += __shfl_xor(a, 1);
    a += __shfl_xor(a, 2);
    a += __shfl_xor(a, 4);
    acc[e] = fmaxf(a + benc[e], 0.0f);
  }

  // ---- Decoder: this lane's 24 outputs, kept in registers ----
  float bd[24];
  #pragma unroll
  for (int q = 0; q < 6; ++q) {
    const float4 bv = *(const float4*)(bdec + sub * 24 + 4 * q);
    bd[4*q+0]=bv.x; bd[4*q+1]=bv.y; bd[4*q+2]=bv.z; bd[4*q+3]=bv.w;
  }
  float o[24];
  float s = 0.0f;
  #pragma unroll
  for (int q = 0; q < 24; ++q) {
    const float* w = Wdec + (sub * 24 + q) * 16;
    const float4 w0 = *(const float4*)(w);
    const float4 w1 = *(const float4*)(w + 4);
    const float4 w2 = *(const float4*)(w + 8);
    const float4 w3 = *(const float4*)(w + 12);
    float v = bd[q];
    v = fmaf(w0.x, acc[0],  v); v = fmaf(w0.y, acc[1],  v);
    v = fmaf(w0.z, acc[2],  v); v = fmaf(w0.w, acc[3],  v);
    v = fmaf(w1.x, acc[4],  v); v = fmaf(w1.y, acc[5],  v);
    v = fmaf(w1.z, acc[6],  v); v = fmaf(w1.w, acc[7],  v);
    v = fmaf(w2.x, acc[8],  v); v = fmaf(w2.y, acc[9],  v);
    v = fmaf(w2.z, acc[10], v); v = fmaf(w2.w, acc[11], v);
    v = fmaf(w3.x, acc[12], v); v = fmaf(w3.y, acc[13], v);
    v = fmaf(w3.z, acc[14], v); v = fmaf(w3.w, acc[15], v);
    v = fmaxf(v, 0.0f);
    o[q] = v;
    s += __builtin_amdgcn_exp2f(v * L2E);
  }
  // ---- Softmax denominator across the 8-lane group ----
  s += __shfl_xor(s, 1);
  s += __shfl_xor(s, 2);
  s += __shfl_xor(s, 4);
  const float inv = __builtin_amdgcn_rcpf(s);

  // ---- y = softmax(out)*out, 3 coalesced float4-pair stores ----
  #pragma unroll
  for (int t = 0; t < 3; ++t) {
    const int cr = 3 * sub + t;
    float* dst = y + base + (cr >> 3) * 65536 + (cr & 7) * 256;
    float r[8];
    #pragma unroll
    for (int c = 0; c < 8; ++c) {
      const float ov = o[t * 8 + c];
      r[c] = __builtin_amdgcn_exp2f(ov * L2E) * inv * ov;
    }
    const float4 s0 = {r[0], r[1], r[2], r[3]};
    const float4 s1 = {r[4], r[5], r[6], r[7]};
    *(float4*)(dst)     = s0;
    *(float4*)(dst + 4) = s1;
  }
}

extern "C" void kernel_launch(void* const* d_in, const int* in_sizes, int n_in,
                              void* d_out, int out_size, void* d_ws, size_t ws_size,
                              hipStream_t stream) {
  const float* x    = (const float*)d_in[0];
  const float* Wenc = (const float*)d_in[1];
  const float* benc = (const float*)d_in[2];
  const float* Wdec = (const float*)d_in[3];
  const float* bdec = (const float*)d_in[4];
  float* y = (float*)d_out;
  dim3 grid(NPATCH / 32), block(256);
  hipLaunchKernelGGL(spatial_attn, grid, block, 0, stream, x, Wenc, benc, Wdec, bdec, y);
}

// Round 4
// 219.469 us; speedup vs baseline: 1.8330x; 1.8330x over previous
//
#include <hip/hip_runtime.h>

// SpatialAttention fp32: B=128, C=3, H=W=256, 8x8 patches, FEAT=192, ENC=16.
// R4: 4 waves/block share the SAME 64 patches (patch = lane); wave w owns
// feature chunk [48w,48w+48). Weight indices are wave-uniform (readfirstlane)
// -> pure s_load / constant-cache path (R3's per-lane VMEM weight storm was
// the 288us regression). 8192 waves (4x R2) for latency hiding; o[48] kept in
// registers so the decoder runs once. Cross-wave reduce via padded LDS.

constexpr int NPATCH = 128 * 32 * 32;
constexpr float L2E  = 1.4426950408889634f;

__global__ __launch_bounds__(256, 4) void spatial_attn(
    const float* __restrict__ x,      // [128][3][256][256]
    const float* __restrict__ Wenc,   // [16][192]
    const float* __restrict__ benc,   // [16]
    const float* __restrict__ Wdec,   // [192][16]
    const float* __restrict__ bdec,   // [192]
    float* __restrict__ y)            // [128][3][256][256]
{
  __shared__ float encl[16 * 257];    // [e][wv*64+lane], pad 257 -> lane-consecutive banks
  __shared__ float sls[256];

  const int tid  = threadIdx.x;
  const int lane = tid & 63;
  const int wv   = __builtin_amdgcn_readfirstlane(tid >> 6);  // provably uniform
  const int p    = blockIdx.x * 64 + lane;                    // one patch per lane
  const int b    = p >> 10;
  const int ii   = (p >> 5) & 31;
  const int jj   = p & 31;
  const size_t base = (size_t)b * 196608 + (size_t)ii * 2048 + (size_t)jj * 8;

  // ---- Load this wave's 48 features (rows 6wv..6wv+5), coalesced float4 ----
  float xv[48];
  #pragma unroll
  for (int t = 0; t < 6; ++t) {
    const int cr = 6 * wv + t;
    const float* src = x + base + (cr >> 3) * 65536 + (cr & 7) * 256;
    const float4 v0 = *(const float4*)(src);
    const float4 v1 = *(const float4*)(src + 4);
    xv[t*8+0]=v0.x; xv[t*8+1]=v0.y; xv[t*8+2]=v0.z; xv[t*8+3]=v0.w;
    xv[t*8+4]=v1.x; xv[t*8+5]=v1.y; xv[t*8+6]=v1.z; xv[t*8+7]=v1.w;
  }

  // ---- Encoder partial over 48 features (weights via s_load) ----
  float acc[16];
  #pragma unroll
  for (int e = 0; e < 16; ++e) {
    const float* w = Wenc + e * 192 + wv * 48;   // wave-uniform
    float a = 0.0f;
    #pragma unroll
    for (int q = 0; q < 48; ++q) a = fmaf(w[q], xv[q], a);
    acc[e] = a;
  }

  // ---- Cross-wave reduction of acc[16] ----
  #pragma unroll
  for (int e = 0; e < 16; ++e) encl[e * 257 + tid] = acc[e];
  __syncthreads();
  #pragma unroll
  for (int e = 0; e < 16; ++e) {
    const float a = encl[e * 257 + lane]       + encl[e * 257 + 64  + lane]
                  + encl[e * 257 + 128 + lane] + encl[e * 257 + 192 + lane];
    acc[e] = fmaxf(a + benc[e], 0.0f);
  }

  // ---- Decoder: this wave's 48 outputs, kept in registers ----
  float o[48];
  float s = 0.0f;
  #pragma unroll
  for (int q = 0; q < 48; ++q) {
    const int f = wv * 48 + q;
    const float* w = Wdec + f * 16;              // wave-uniform
    float v = bdec[f];
    #pragma unroll
    for (int e = 0; e < 16; ++e) v = fmaf(w[e], acc[e], v);
    v = fmaxf(v, 0.0f);
    o[q] = v;
    s += __builtin_amdgcn_exp2f(v * L2E);        // out>=0, bounded: no max-sub needed
  }

  // ---- Softmax denominator across the 4 waves ----
  sls[tid] = s;
  __syncthreads();
  const float st = sls[lane] + sls[lane + 64] + sls[lane + 128] + sls[lane + 192];
  const float inv = __builtin_amdgcn_rcpf(st);

  // ---- y = softmax(out)*out, coalesced float4 stores ----
  #pragma unroll
  for (int t = 0; t < 6; ++t) {
    const int cr = 6 * wv + t;
    float* dst = y + base + (cr >> 3) * 65536 + (cr & 7) * 256;
    float r[8];
    #pragma unroll
    for (int c = 0; c < 8; ++c) {
      const float ov = o[t * 8 + c];
      r[c] = __builtin_amdgcn_exp2f(ov * L2E) * inv * ov;
    }
    const float4 s0 = {r[0], r[1], r[2], r[3]};
    const float4 s1 = {r[4], r[5], r[6], r[7]};
    *(float4*)(dst)     = s0;
    *(float4*)(dst + 4) = s1;
  }
}

extern "C" void kernel_launch(void* const* d_in, const int* in_sizes, int n_in,
                              void* d_out, int out_size, void* d_ws, size_t ws_size,
                              hipStream_t stream) {
  const float* x    = (const float*)d_in[0];
  const float* Wenc = (const float*)d_in[1];
  const float* benc = (const float*)d_in[2];
  const float* Wdec = (const float*)d_in[3];
  const float* bdec = (const float*)d_in[4];
  float* y = (float*)d_out;
  dim3 grid(NPATCH / 64), block(256);
  hipLaunchKernelGGL(spatial_attn, grid, block, 0, stream, x, Wenc, benc, Wdec, bdec, y);
}